// Round 13
// baseline (399.649 us; speedup 1.0000x reference)
//
#include <hip/hip_runtime.h>

#define BB 4
#define CC 96
#define HH 64
#define WW 64
#define LL 4096
#define KK 3
#define RR 6
#define NN 16

__device__ __forceinline__ float geluf(float x){
    return 0.5f * x * (1.0f + erff(x * 0.70710678118654752f));
}
__device__ __forceinline__ float softplusf(float x){
    return fmaxf(x, 0.0f) + log1pf(expf(-fabsf(x)));
}
__device__ __forceinline__ float sigmoidf(float x){
    return 1.0f / (1.0f + expf(-x));
}

// ---------------- Kernel A+D fused: spatial mean (384 blocks) || rpe resize (1536) ----
// Both roles are tiny-register -> no co-compile register coupling (R11/R12 lesson:
// role fusion only works when the roles have compatible register footprints).
__global__ __launch_bounds__(256) void k_meanrpe(const float* __restrict__ x, float* __restrict__ xc,
                                                 const float* __restrict__ rpet, float* __restrict__ rpe){
    int blk = blockIdx.x;
    if (blk < BB*CC){
        const float* p = x + (size_t)blk * LL;
        float s = 0.f;
        for (int i = threadIdx.x; i < LL; i += 256) s += p[i];
        __shared__ float red[256];
        red[threadIdx.x] = s; __syncthreads();
        for (int st = 128; st > 0; st >>= 1){
            if (threadIdx.x < st) red[threadIdx.x] += red[threadIdx.x + st];
            __syncthreads();
        }
        if (threadIdx.x == 0) xc[blk] = red[0] * (1.0f / LL);
    } else {
        int gid = (blk - BB*CC) * 256 + threadIdx.x; // C*L
        int l = gid & (LL-1); int c = gid >> 12;
        int h = l >> 6, w = l & 63;
        float sy = fmaxf((h + 0.5f) * (7.0f/64.0f) - 0.5f, 0.f);
        float sx = fmaxf((w + 0.5f) * (7.0f/64.0f) - 0.5f, 0.f);
        int y0 = (int)floorf(sy); int x0 = (int)floorf(sx);
        float wy = sy - (float)y0, wx = sx - (float)x0;
        int y1 = min(y0 + 1, 6), x1i = min(x0 + 1, 6);
        const float* tp = rpet + c * 49;
        float r0 = tp[y0*7 + x0] * (1.f - wy) + tp[y1*7 + x0] * wy;
        float r1 = tp[y0*7 + x1i] * (1.f - wy) + tp[y1*7 + x1i] * wy;
        rpe[gid] = r0 * (1.f - wx) + r1 * wx;
    }
}

// ---------------- Kernel B: channel-attention MLP ----------------
__global__ __launch_bounds__(128) void k_ca(const float* __restrict__ xc,
                     const float* __restrict__ w1, const float* __restrict__ b1,
                     const float* __restrict__ w2, const float* __restrict__ b2,
                     float* __restrict__ ca){
    int b = blockIdx.x;
    int t = threadIdx.x;
    __shared__ float hid[CC/16];
    if (t < CC/16){
        float a = b1[t];
        for (int d = 0; d < CC; d++) a += w1[t*CC + d] * xc[b*CC + d];
        hid[t] = geluf(a);
    }
    __syncthreads();
    if (t < CC){
        float a = b2[t];
        #pragma unroll
        for (int i = 0; i < CC/16; i++) a += w2[t*(CC/16) + i] * hid[i];
        ca[b*CC + t] = sigmoidf(a);
    }
}

// ---------------- Kernel C: depthwise 9x9 conv, 4 px/thread sliding window (R10) -----
__global__ __launch_bounds__(256) void k_conv(const float* __restrict__ x, const float* __restrict__ w,
                       const float* __restrict__ bias, const float* __restrict__ ca,
                       float* __restrict__ x1){
    int tid4 = blockIdx.x * 256 + threadIdx.x;   // B*C*H*16 groups
    int wq4 = (tid4 & 15) * 4;                   // w0 of the 4-pixel group
    int rest = tid4 >> 4;
    int h = rest & 63;
    int bc = rest >> 6;
    int c = bc % CC; int b = bc / CC;
    const float* xp = x + (size_t)bc * LL;
    const float* wp = w + c * 81;
    float a0 = 0.f, a1 = 0.f, a2 = 0.f, a3 = 0.f;
    #pragma unroll
    for (int ky = 0; ky < 9; ky++){
        int yy = h + ky - 4;
        if (yy < 0 || yy >= HH) continue;
        const float4* row4 = (const float4*)(xp + yy*WW);
        int g = wq4 >> 2;
        float4 q0 = (wq4 >= 4)  ? row4[g-1] : make_float4(0.f,0.f,0.f,0.f);
        float4 q1 = row4[g];
        float4 q2 = (wq4 < 60)  ? row4[g+1] : make_float4(0.f,0.f,0.f,0.f);
        float v[12] = {q0.x,q0.y,q0.z,q0.w, q1.x,q1.y,q1.z,q1.w, q2.x,q2.y,q2.z,q2.w};
        const float* wr = wp + ky*9;
        #pragma unroll
        for (int kx = 0; kx < 9; kx++){
            float wk = wr[kx];
            a0 = fmaf(v[kx],   wk, a0);
            a1 = fmaf(v[kx+1], wk, a1);
            a2 = fmaf(v[kx+2], wk, a2);
            a3 = fmaf(v[kx+3], wk, a3);
        }
    }
    float sc = ca[b*CC + c];
    float bb = bias[c];
    float4 o = make_float4((a0+bb)*sc, (a1+bb)*sc, (a2+bb)*sc, (a3+bb)*sc);
    *(float4*)(x1 + (size_t)bc*LL + h*WW + wq4) = o;
}

// ---------------- Kernel E v2: LayerNorm(C)+GELU+1x1, 32-l tiles (512 blocks) --------
__global__ __launch_bounds__(256) void k_off(const float* __restrict__ x1,
                      const float* __restrict__ g, const float* __restrict__ bta,
                      const float* __restrict__ w2,
                      float* __restrict__ posy, float* __restrict__ posx, float* __restrict__ path){
    int blk = blockIdx.x;            // b*128 + tile
    int tile = blk & 127; int b = blk >> 7;
    int li = threadIdx.x & 31;
    int cg = threadIdx.x >> 5;       // 0..7
    int l = tile * 32 + li;
    const float* p = x1 + (size_t)b * CC * LL + l;
    float v[12];
    float s = 0.f, ss = 0.f;
    #pragma unroll
    for (int j = 0; j < 12; j++){
        float t = p[(size_t)(cg*12 + j) * LL];
        v[j] = t; s += t; ss += t*t;
    }
    __shared__ float ls[8][32], lss[8][32];
    ls[cg][li] = s; lss[cg][li] = ss;
    __syncthreads();
    s = 0.f; ss = 0.f;
    #pragma unroll
    for (int g2 = 0; g2 < 8; g2++){ s += ls[g2][li]; ss += lss[g2][li]; }
    float m = s * (1.0f/CC);
    float rstd = rsqrtf(ss*(1.0f/CC) - m*m + 1e-5f);
    float a0 = 0.f, a1 = 0.f, a2 = 0.f;
    #pragma unroll
    for (int j = 0; j < 12; j++){
        int c = cg*12 + j;
        float xn = (v[j]-m)*rstd*g[c] + bta[c];
        float xg = geluf(xn);
        a0 = fmaf(w2[c],      xg, a0);
        a1 = fmaf(w2[CC+c],   xg, a1);
        a2 = fmaf(w2[2*CC+c], xg, a2);
    }
    __shared__ float la[3][8][32];
    la[0][cg][li] = a0; la[1][cg][li] = a1; la[2][cg][li] = a2;
    __syncthreads();
    if (cg < 3){
        float a = 0.f;
        #pragma unroll
        for (int g2 = 0; g2 < 8; g2++) a += la[cg][g2][li];
        int h = l >> 6, ww = l & 63;
        if (cg == 0)      posy[b*LL + l] = tanhf(a)*(1.0f/63.0f) + ((2*h+1)*(1.0f/63.0f) - 1.0f);
        else if (cg == 1) posx[b*LL + l] = tanhf(a)*(1.0f/63.0f) + ((2*ww+1)*(1.0f/63.0f) - 1.0f);
        else              path[b*LL + l] = tanhf(a) + ((l + 0.5f)*(2.0f/4095.0f) - 1.0f);
    }
}

// ---------------- bilinear sample, zero padding ----------------
__device__ __forceinline__ float bilin0(const float* __restrict__ img, float gx, float gy){
    float fx = (gx + 1.f) * 31.5f;   // (W-1)/2 = 31.5
    float fy = (gy + 1.f) * 31.5f;
    float x0f = floorf(fx), y0f = floorf(fy);
    float wx = fx - x0f, wy = fy - y0f;
    int x0 = (int)x0f, y0 = (int)y0f;
    float acc = 0.f;
    bool vx0 = (x0 >= 0) & (x0 < WW), vx1 = (x0+1 >= 0) & (x0+1 < WW);
    bool vy0 = (y0 >= 0) & (y0 < HH), vy1 = (y0+1 >= 0) & (y0+1 < HH);
    if (vy0 & vx0) acc += img[y0*WW + x0]       * (1.f-wx) * (1.f-wy);
    if (vy0 & vx1) acc += img[y0*WW + x0+1]     * wx       * (1.f-wy);
    if (vy1 & vx0) acc += img[(y0+1)*WW + x0]   * (1.f-wx) * wy;
    if (vy1 & vx1) acc += img[(y0+1)*WW + x0+1] * wx       * wy;
    return acc;
}

// ---------------- Kernel F+S fused: bitonic argsort (4 blocks) || grid-sample (rest) ----
typedef unsigned long long u64s;
__device__ __forceinline__ u64s shflx64(u64s x, int m){
    int lo = __shfl_xor((int)(unsigned)x, m);
    int hi = __shfl_xor((int)(unsigned)(x >> 32), m);
    return ((u64s)(unsigned)hi << 32) | (unsigned)lo;
}
__device__ __forceinline__ void cex(u64s& a, u64s& b, bool up){
    u64s mn = a < b ? a : b;
    u64s mx = a < b ? b : a;
    a = up ? mn : mx;
    b = up ? mx : mn;
}
__global__ __launch_bounds__(1024) void k_sortsample(
        const float* __restrict__ path, int* __restrict__ idx, int* __restrict__ inv,
        const float* __restrict__ x, const float* __restrict__ rpe,
        const float* __restrict__ posy, const float* __restrict__ posx,
        float* __restrict__ xd){
    int blk = blockIdx.x;
    if (blk < BB){
        // -------- sort role: one block per batch --------
        int b = blk;
        int t = threadIdx.x;
        __shared__ u64s lds[LL];
        u64s v[4];
        #pragma unroll
        for (int r = 0; r < 4; r++){
            int e = t*4 + r;
            unsigned u = __float_as_uint(path[b*LL + e]);
            u ^= (u >> 31) ? 0xFFFFFFFFu : 0x80000000u;   // monotonic float->uint
            v[r] = ((u64s)u << 32) | (unsigned)e;
        }
        for (int kk = 2; kk <= LL; kk <<= 1){
            for (int j = kk >> 1; j > 0; j >>= 1){
                if (j >= 256){
                    __syncthreads();
                    #pragma unroll
                    for (int r = 0; r < 4; r++) lds[t*4 + r] = v[r];
                    __syncthreads();
                    #pragma unroll
                    for (int r = 0; r < 4; r++){
                        int e = t*4 + r;
                        u64s pv = lds[e ^ j];
                        bool up    = ((e & kk) == 0);
                        bool lower = ((e & j) == 0);
                        u64s mn = v[r] < pv ? v[r] : pv;
                        u64s mx = v[r] < pv ? pv : v[r];
                        v[r] = (up == lower) ? mn : mx;
                    }
                } else if (j >= 4){
                    int m = j >> 2;
                    #pragma unroll
                    for (int r = 0; r < 4; r++){
                        u64s pv = shflx64(v[r], m);
                        bool up    = (((t*4 + r) & kk) == 0);
                        bool lower = ((t & m) == 0);
                        u64s mn = v[r] < pv ? v[r] : pv;
                        u64s mx = v[r] < pv ? pv : v[r];
                        v[r] = (up == lower) ? mn : mx;
                    }
                } else if (j == 2){
                    bool up = (((t*4) & kk) == 0);
                    cex(v[0], v[2], up);
                    cex(v[1], v[3], up);
                } else { // j == 1
                    if (kk == 2){
                        cex(v[0], v[1], true);
                        cex(v[2], v[3], false);
                    } else {
                        bool up = (((t*4) & kk) == 0);
                        cex(v[0], v[1], up);
                        cex(v[2], v[3], up);
                    }
                }
            }
        }
        #pragma unroll
        for (int r = 0; r < 4; r++){
            int e = t*4 + r;
            int id = (int)(unsigned)(v[r] & 0xFFFFFFFFu);
            idx[b*LL + e] = id;
            inv[b*LL + id] = e;
        }
    } else {
        // -------- sample role: x grid-sample + rpe grid-sample -> xd --------
        int gid = (blk - BB) * 1024 + threadIdx.x; // B*C*L
        int l = gid & (LL-1); int bc = gid >> 12;
        int b = bc / CC; int c = bc % CC;
        float gy = posy[b*LL + l], gx = posx[b*LL + l];
        float v = bilin0(x + (size_t)bc * LL, gx, gy);
        int h = l >> 6, w = l & 63;
        float ky = h * (128.0f/3969.0f) - 1.0f;  // linspace(0,64,64)/63*2-1
        float kx = w * (128.0f/3969.0f) - 1.0f;
        float v2 = bilin0(rpe + (size_t)c * LL, (kx - gx) * 0.5f, (ky - gy) * 0.5f);
        xd[gid] = v + v2;
    }
}

// ---------------- Kernel G01: projection k=0 AND k=1 from ONE staged x-tile ----------
// xs[1] = xs[0] reversed, so a single 96x64 x-tile serves both scan directions:
// lane at column l emits k0 outputs at l and k1 outputs at LL-1-l (reversed-contiguous
// stores, still coalesced). Compute runs sequentially per k -> register pressure
// identical to the verified 3-wave proj; staging traffic and block count halve.
// Standalone kernel (separate regalloc -> no R11/R12 co-compile coupling).
__global__ __launch_bounds__(192, 1) void k_proj01(const float* __restrict__ x,
    const float* __restrict__ xpw, const float* __restrict__ dtw,
    const float* __restrict__ dtb, float* __restrict__ dt,
    float* __restrict__ Bst, float* __restrict__ Cst){
    int blk = blockIdx.x;          // B*64 blocks
    int ltile = blk & 63; int b = blk >> 6;
    int lane = threadIdx.x & 63;
    int w = threadIdx.x >> 6;      // 0..2
    int l = ltile * 64 + lane;
    const float* xp = x + (size_t)b * CC * LL + l;

    __shared__ float vsh[CC*64];   // 24 KB
    #pragma unroll
    for (int j = 0; j < 32; j++){
        int d = w*32 + j;
        vsh[d*64 + lane] = xp[(size_t)d * LL];
    }
    __syncthreads();

    #pragma unroll
    for (int kk = 0; kk < 2; kk++){
        const float* __restrict__ Wk = xpw + kk*38*CC;
        int bk = b * KK + kk;
        int lk = (kk == 0) ? l : (LL-1-l);
        if (w == 0){
            float acc[RR];
            #pragma unroll
            for (int i = 0; i < RR; i++) acc[i] = 0.f;
            for (int d = 0; d < CC; d++){
                float vv = vsh[d*64 + lane];
                #pragma unroll
                for (int i = 0; i < RR; i++) acc[i] = fmaf(Wk[i*CC + d], vv, acc[i]);
            }
            const float* __restrict__ Dw = dtw + kk*CC*RR;
            const float* __restrict__ Db = dtb + kk*CC;
            float* dtp = dt + (size_t)bk * CC * LL + lk;
            #pragma unroll 8
            for (int d = 0; d < CC; d++){
                float sdt = Db[d];
                #pragma unroll
                for (int r = 0; r < RR; r++) sdt = fmaf(acc[r], Dw[d*RR + r], sdt);
                dtp[(size_t)d * LL] = softplusf(sdt);
            }
        } else if (w == 1){
            float acc[NN];
            #pragma unroll
            for (int i = 0; i < NN; i++) acc[i] = 0.f;
            for (int d = 0; d < CC; d++){
                float vv = vsh[d*64 + lane];
                #pragma unroll
                for (int i = 0; i < NN; i++) acc[i] = fmaf(Wk[(RR + i)*CC + d], vv, acc[i]);
            }
            size_t base = ((size_t)bk * LL + lk) * NN;
            #pragma unroll
            for (int q = 0; q < 4; q++){
                float4 o; o.x = acc[q*4]; o.y = acc[q*4+1]; o.z = acc[q*4+2]; o.w = acc[q*4+3];
                *(float4*)(Bst + base + q*4) = o;
            }
        } else {
            float acc[NN];
            #pragma unroll
            for (int i = 0; i < NN; i++) acc[i] = 0.f;
            for (int d = 0; d < CC; d++){
                float vv = vsh[d*64 + lane];
                #pragma unroll
                for (int i = 0; i < NN; i++) acc[i] = fmaf(Wk[(RR + NN + i)*CC + d], vv, acc[i]);
            }
            size_t base = ((size_t)bk * LL + lk) * NN;
            #pragma unroll
            for (int q = 0; q < 4; q++){
                float4 o; o.x = acc[q*4]; o.y = acc[q*4+1]; o.z = acc[q*4+2]; o.w = acc[q*4+3];
                *(float4*)(Cst + base + q*4) = o;
            }
        }
    }
}

// ---------------- Kernel G2: projection k=2 (R10 3-wave body, k hard-wired) ----------
__global__ __launch_bounds__(192, 1) void k_proj2(const float* __restrict__ xd,
    const int* __restrict__ indices, const float* __restrict__ xpw, const float* __restrict__ dtw,
    const float* __restrict__ dtb, float* __restrict__ u2, float* __restrict__ dt,
    float* __restrict__ Bst, float* __restrict__ Cst){
    int blk = blockIdx.x;          // B*64 blocks
    int ltile = blk & 63; int b = blk >> 6;
    int lane = threadIdx.x & 63;
    int w = threadIdx.x >> 6;      // 0..2
    const float* __restrict__ Wk = xpw + 2*38*CC;
    int bk = b * KK + 2;
    int l = ltile * 64 + lane;
    int srcl = indices[b*LL + l];
    const float* xp = xd + (size_t)b * CC * LL + srcl;

    __shared__ float vsh[CC*64];   // 24 KB
    #pragma unroll
    for (int j = 0; j < 32; j++){
        int d = w*32 + j;
        vsh[d*64 + lane] = xp[(size_t)d * LL];
    }
    __syncthreads();

    if (w == 0){
        float acc[RR];
        #pragma unroll
        for (int i = 0; i < RR; i++) acc[i] = 0.f;
        for (int d = 0; d < CC; d++){
            float vv = vsh[d*64 + lane];
            #pragma unroll
            for (int i = 0; i < RR; i++) acc[i] = fmaf(Wk[i*CC + d], vv, acc[i]);
        }
        const float* __restrict__ Dw = dtw + 2*CC*RR;
        const float* __restrict__ Db = dtb + 2*CC;
        float* dtp = dt + (size_t)bk * CC * LL + l;
        #pragma unroll 8
        for (int d = 0; d < CC; d++){
            float sdt = Db[d];
            #pragma unroll
            for (int r = 0; r < RR; r++) sdt = fmaf(acc[r], Dw[d*RR + r], sdt);
            dtp[(size_t)d * LL] = softplusf(sdt);
        }
    } else if (w == 1){
        float acc[NN];
        #pragma unroll
        for (int i = 0; i < NN; i++) acc[i] = 0.f;
        for (int d = 0; d < CC; d++){
            float vv = vsh[d*64 + lane];
            #pragma unroll
            for (int i = 0; i < NN; i++) acc[i] = fmaf(Wk[(RR + i)*CC + d], vv, acc[i]);
        }
        size_t base = ((size_t)bk * LL + l) * NN;
        #pragma unroll
        for (int q = 0; q < 4; q++){
            float4 o; o.x = acc[q*4]; o.y = acc[q*4+1]; o.z = acc[q*4+2]; o.w = acc[q*4+3];
            *(float4*)(Bst + base + q*4) = o;
        }
    } else {
        float acc[NN];
        #pragma unroll
        for (int i = 0; i < NN; i++) acc[i] = 0.f;
        for (int d = 0; d < CC; d++){
            float vv = vsh[d*64 + lane];
            #pragma unroll
            for (int i = 0; i < NN; i++) acc[i] = fmaf(Wk[(RR + NN + i)*CC + d], vv, acc[i]);
        }
        size_t base = ((size_t)bk * LL + l) * NN;
        #pragma unroll
        for (int q = 0; q < 4; q++){
            float4 o; o.x = acc[q*4]; o.y = acc[q*4+1]; o.z = acc[q*4+2]; o.w = acc[q*4+3];
            *(float4*)(Cst + base + q*4) = o;
        }
        float* up = u2 + (size_t)b * CC * LL + l;
        #pragma unroll 8
        for (int d = 0; d < CC; d++) up[(size_t)d * LL] = vsh[d*64 + lane];
    }
}

// ---------------- Kernel H: merged selective scan (R8-exact, measured ~72us) ---------
#define SEG 128        // segments
#define TL 32          // steps per segment
#define SROW 17        // padded row stride for sA/sB (words)
#define XROW 32        // row stride for sS/yl (words), XOR-swizzled, 16B-aligned
template<int KIND>
__device__ __forceinline__ void scan_body(int b, int d, const float* __restrict__ usrc,
    const float* __restrict__ dt, const float* __restrict__ Bst, const float* __restrict__ Cst,
    const float* __restrict__ Alog, const float* __restrict__ Ds, float* __restrict__ ys,
    float* sA, float* sB, float* sS, float* yl){
    int bk = b * KK + KIND;
    int tid = threadIdx.x;
    int ng = tid & 3;          // n = 4*ng + j
    int seg = tid >> 2;        // 0..127
    int t0 = seg * TL;
    int xsw = (seg & 7) << 2;  // XOR swizzle for sS/yl rows

    const float4 A4 = *(const float4*)(Alog + (KIND*CC + d)*NN + 4*ng);
    const float L2E = 1.4426950408889634f;
    float A2[4] = { -__expf(A4.x)*L2E, -__expf(A4.y)*L2E, -__expf(A4.z)*L2E, -__expf(A4.w)*L2E };
    float Dv = Ds[KIND*CC + d];

    const float* dtp = dt + ((size_t)bk * CC + d) * LL + t0;
    const float* ub = (KIND == 1)
        ? usrc + ((size_t)b*CC + d) * LL + (LL-4-t0)
        : usrc + ((size_t)b*CC + d) * LL + t0;
    const float* Bp = Bst + ((size_t)bk * LL + t0) * NN + 4*ng;
    const float* Cp = Cst + ((size_t)bk * LL + t0) * NN + 4*ng;
    float* yp = ys + ((size_t)bk * CC + d) * LL + t0;

    // Phase 1: local scan from h=0; emit y_loc and S (dt prefix sum) to LDS
    float h[4] = {0.f,0.f,0.f,0.f};
    float S = 0.f;
    for (int t = 0; t < TL; t += 4){
        float4 dq = *(const float4*)(dtp + t);
        float4 uq = (KIND == 1) ? *(const float4*)(ub - t) : *(const float4*)(ub + t);
        float4 Bq[4], Cq[4];
        #pragma unroll
        for (int i = 0; i < 4; i++){
            Bq[i] = *(const float4*)(Bp + (t+i)*NN);
            Cq[i] = *(const float4*)(Cp + (t+i)*NN);
        }
        float dd[4] = {dq.x, dq.y, dq.z, dq.w};
        float uu[4];
        if (KIND == 1){ uu[0]=uq.w; uu[1]=uq.z; uu[2]=uq.y; uu[3]=uq.x; }
        else          { uu[0]=uq.x; uu[1]=uq.y; uu[2]=uq.z; uu[3]=uq.w; }
        float sv[4], pv[4];
        #pragma unroll
        for (int i = 0; i < 4; i++){
            float du = dd[i] * uu[i];
            float bb[4] = {Bq[i].x, Bq[i].y, Bq[i].z, Bq[i].w};
            float cc[4] = {Cq[i].x, Cq[i].y, Cq[i].z, Cq[i].w};
            float p = 0.f;
            #pragma unroll
            for (int j = 0; j < 4; j++){
                float a = exp2f(dd[i] * A2[j]);
                h[j] = fmaf(a, h[j], du * bb[j]);
                p = fmaf(h[j], cc[j], p);
            }
            S += dd[i];
            sv[i] = S;
            p += __shfl_xor(p, 1);
            p += __shfl_xor(p, 2);
            pv[i] = fmaf(uu[i], Dv, p);
        }
        if (ng == 0){
            int xo = seg*XROW + (t ^ xsw);
            *(float4*)(sS + xo) = make_float4(sv[0], sv[1], sv[2], sv[3]);
            *(float4*)(yl + xo) = make_float4(pv[0], pv[1], pv[2], pv[3]);
        }
    }

    // Phase 2: per-wave shuffle scan over 128 segments (exclusive carries)
    #pragma unroll
    for (int j = 0; j < 4; j++){
        sA[seg*SROW + 4*ng + j] = exp2f(A2[j] * S);
        sB[seg*SROW + 4*ng + j] = h[j];
    }
    __syncthreads();
    {
        int wv = tid >> 6;         // 0..7
        int lane = tid & 63;
        #pragma unroll
        for (int nn = 0; nn < 2; nn++){
            int n = 2*wv + nn;
            float a1 = sA[(2*lane)*SROW + n],   b1 = sB[(2*lane)*SROW + n];
            float a2 = sA[(2*lane+1)*SROW + n], b2 = sB[(2*lane+1)*SROW + n];
            float ca = a1 * a2;
            float cb = fmaf(a2, b1, b2);
            #pragma unroll
            for (int off = 1; off < 64; off <<= 1){
                float ta = __shfl_up(ca, off);
                float tb = __shfl_up(cb, off);
                if (lane >= off){
                    cb = fmaf(ca, tb, cb);
                    ca *= ta;
                }
            }
            float cb_prev = __shfl_up(cb, 1);
            if (lane == 0) cb_prev = 0.f;
            sA[(2*lane)*SROW + n]   = cb_prev;
            sA[(2*lane+1)*SROW + n] = fmaf(a1, cb_prev, b1);
        }
    }
    __syncthreads();
    float hc[4];
    #pragma unroll
    for (int j = 0; j < 4; j++) hc[j] = sA[seg*SROW + 4*ng + j];

    // Phase 3: y = y_loc + C·(exp2(A2·S)∘hc) — per-step independent
    for (int t = 0; t < TL; t += 4){
        int xo = seg*XROW + (t ^ xsw);
        float4 sq = *(const float4*)(sS + xo);
        float4 Cq[4];
        #pragma unroll
        for (int i = 0; i < 4; i++) Cq[i] = *(const float4*)(Cp + (t+i)*NN);
        float sv[4] = {sq.x, sq.y, sq.z, sq.w};
        float yo[4];
        #pragma unroll
        for (int i = 0; i < 4; i++){
            float cc[4] = {Cq[i].x, Cq[i].y, Cq[i].z, Cq[i].w};
            float corr = 0.f;
            #pragma unroll
            for (int j = 0; j < 4; j++){
                float P = exp2f(sv[i] * A2[j]);
                corr = fmaf(P * hc[j], cc[j], corr);
            }
            corr += __shfl_xor(corr, 1);
            corr += __shfl_xor(corr, 2);
            yo[i] = corr;
        }
        if (ng == 0){
            float4 ylq = *(const float4*)(yl + xo);
            float4 o = make_float4(ylq.x + yo[0], ylq.y + yo[1], ylq.z + yo[2], ylq.w + yo[3]);
            *(float4*)(yp + t) = o;
        }
    }
}

__global__ __launch_bounds__(512) void k_scan_all(const float* __restrict__ x, const float* __restrict__ u2,
    const float* __restrict__ dt, const float* __restrict__ Bst, const float* __restrict__ Cst,
    const float* __restrict__ Alog, const float* __restrict__ Ds, float* __restrict__ ys){
    __shared__ float sA[SEG*SROW];
    __shared__ float sB[SEG*SROW];
    __shared__ float sS[SEG*XROW];
    __shared__ float yl[SEG*XROW];   // total LDS 50176 B
    int blk = blockIdx.x;            // KK*BB*CC
    int k = blk / (BB*CC);
    int r = blk % (BB*CC);
    int d = r % CC; int b = r / CC;
    if (k == 0)      scan_body<0>(b, d, x,  dt, Bst, Cst, Alog, Ds, ys, sA, sB, sS, yl);
    else if (k == 1) scan_body<1>(b, d, x,  dt, Bst, Cst, Alog, Ds, ys, sA, sB, sS, yl);
    else             scan_body<2>(b, d, u2, dt, Bst, Cst, Alog, Ds, ys, sA, sB, sS, yl);
}

// ---------------- Kernel I: combine 3 paths + transpose, 16-l tiles (R10) ------------
__global__ __launch_bounds__(256) void k_comb(const float* __restrict__ ys, const int* __restrict__ inv,
                                              float* __restrict__ out){
    int tile = blockIdx.x & 255; int b = blockIdx.x >> 8;
    int l0 = tile * 16;
    __shared__ float t0[CC * 17];
    __shared__ int invs[16];
    if (threadIdx.x < 16) invs[threadIdx.x] = inv[b*LL + l0 + threadIdx.x];
    __syncthreads();
    const float* y0p = ys + (size_t)(b*KK + 0) * CC * LL;
    const float* y1p = ys + (size_t)(b*KK + 1) * CC * LL;
    const float* y2p = ys + (size_t)(b*KK + 2) * CC * LL;
    #pragma unroll
    for (int it = 0; it < 6; it++){
        int e = it * 256 + threadIdx.x;    // 0..1535
        int li = e & 15; int c = e >> 4;
        int l = l0 + li;
        float v = y0p[(size_t)c*LL + l] + y1p[(size_t)c*LL + (LL-1-l)] + y2p[(size_t)c*LL + invs[li]];
        t0[c*17 + li] = v * (1.0f/3.0f);
    }
    __syncthreads();
    #pragma unroll
    for (int it = 0; it < 6; it++){
        int e = it * 256 + threadIdx.x;
        int c = e % CC; int li = e / CC;
        out[((size_t)b*LL + l0 + li) * CC + c] = t0[c*17 + li];
    }
}

extern "C" void kernel_launch(void* const* d_in, const int* in_sizes, int n_in,
                              void* d_out, int out_size, void* d_ws, size_t ws_size,
                              hipStream_t stream){
    const float* x    = (const float*)d_in[0];
    const float* xpw  = (const float*)d_in[1];
    const float* dtw  = (const float*)d_in[2];
    const float* dtb  = (const float*)d_in[3];
    const float* Alog = (const float*)d_in[4];
    const float* Ds   = (const float*)d_in[5];
    const float* c1w  = (const float*)d_in[6];
    const float* c1b  = (const float*)d_in[7];
    const float* ca1w = (const float*)d_in[8];
    const float* ca1b = (const float*)d_in[9];
    const float* ca2w = (const float*)d_in[10];
    const float* ca2b = (const float*)d_in[11];
    const float* lng  = (const float*)d_in[12];
    const float* lnb  = (const float*)d_in[13];
    const float* c2w  = (const float*)d_in[14];
    const float* rpet = (const float*)d_in[15];
    float* out = (float*)d_out;

    float* ws   = (float*)d_ws;
    float* xc   = ws;                      // 384
    float* ca   = xc + 384;                // 384
    float* x1   = ca + 384;                // B*C*L = 1572864
    float* rpe  = x1 + (size_t)BB*CC*LL;   // C*L = 393216
    float* posy = rpe + (size_t)CC*LL;     // B*L
    float* posx = posy + (size_t)BB*LL;
    float* path = posx + (size_t)BB*LL;
    float* xd   = path + (size_t)BB*LL;    // B*C*L
    int*   idx  = (int*)(xd + (size_t)BB*CC*LL);   // B*L ints
    int*   inv  = idx + (size_t)BB*LL;             // B*L ints
    float* u2   = (float*)(inv + (size_t)BB*LL);   // B*C*L
    float* dtA  = u2 + (size_t)BB*CC*LL;           // B*K*C*L = 4718592
    float* Bst  = dtA + (size_t)BB*KK*CC*LL;       // B*K*L*N = 786432
    float* Cst  = Bst + (size_t)BB*KK*LL*NN;
    float* ysA  = Cst + (size_t)BB*KK*LL*NN;       // B*K*C*L

    k_meanrpe  <<<BB*CC + (CC*LL)/256, 256, 0, stream>>>(x, xc, rpet, rpe);
    k_ca       <<<BB, 128, 0, stream>>>(xc, ca1w, ca1b, ca2w, ca2b, ca);
    k_proj01   <<<BB*64, 192, 0, stream>>>(x, xpw, dtw, dtb, dtA, Bst, Cst);
    k_conv     <<<(BB*CC*LL/4)/256, 256, 0, stream>>>(x, c1w, c1b, ca, x1);
    k_off      <<<BB*128, 256, 0, stream>>>(x1, lng, lnb, c2w, posy, posx, path);
    k_sortsample<<<BB + (BB*CC*LL)/1024, 1024, 0, stream>>>(path, idx, inv, x, rpe, posy, posx, xd);
    k_proj2    <<<BB*64, 192, 0, stream>>>(xd, idx, xpw, dtw, dtb, u2, dtA, Bst, Cst);
    k_scan_all <<<KK*BB*CC, 512, 0, stream>>>(x, u2, dtA, Bst, Cst, Alog, Ds, ysA);
    k_comb     <<<BB*256, 256, 0, stream>>>(ysA, inv, out);
}

// Round 14
// 330.774 us; speedup vs baseline: 1.2082x; 1.2082x over previous
//
#include <hip/hip_runtime.h>

#define BB 4
#define CC 96
#define HH 64
#define WW 64
#define LL 4096
#define KK 3
#define RR 6
#define NN 16

__device__ __forceinline__ float geluf(float x){
    return 0.5f * x * (1.0f + erff(x * 0.70710678118654752f));
}
__device__ __forceinline__ float softplusf(float x){
    return fmaxf(x, 0.0f) + log1pf(expf(-fabsf(x)));
}
__device__ __forceinline__ float sigmoidf(float x){
    return 1.0f / (1.0f + expf(-x));
}

// ---------------- Kernel A+D fused: spatial mean (384 blocks) || rpe resize (1536) ----
__global__ __launch_bounds__(256) void k_meanrpe(const float* __restrict__ x, float* __restrict__ xc,
                                                 const float* __restrict__ rpet, float* __restrict__ rpe){
    int blk = blockIdx.x;
    if (blk < BB*CC){
        const float* p = x + (size_t)blk * LL;
        float s = 0.f;
        for (int i = threadIdx.x; i < LL; i += 256) s += p[i];
        __shared__ float red[256];
        red[threadIdx.x] = s; __syncthreads();
        for (int st = 128; st > 0; st >>= 1){
            if (threadIdx.x < st) red[threadIdx.x] += red[threadIdx.x + st];
            __syncthreads();
        }
        if (threadIdx.x == 0) xc[blk] = red[0] * (1.0f / LL);
    } else {
        int gid = (blk - BB*CC) * 256 + threadIdx.x; // C*L
        int l = gid & (LL-1); int c = gid >> 12;
        int h = l >> 6, w = l & 63;
        float sy = fmaxf((h + 0.5f) * (7.0f/64.0f) - 0.5f, 0.f);
        float sx = fmaxf((w + 0.5f) * (7.0f/64.0f) - 0.5f, 0.f);
        int y0 = (int)floorf(sy); int x0 = (int)floorf(sx);
        float wy = sy - (float)y0, wx = sx - (float)x0;
        int y1 = min(y0 + 1, 6), x1i = min(x0 + 1, 6);
        const float* tp = rpet + c * 49;
        float r0 = tp[y0*7 + x0] * (1.f - wy) + tp[y1*7 + x0] * wy;
        float r1 = tp[y0*7 + x1i] * (1.f - wy) + tp[y1*7 + x1i] * wy;
        rpe[gid] = r0 * (1.f - wx) + r1 * wx;
    }
}

// ---------------- Kernel B: channel-attention MLP ----------------
__global__ __launch_bounds__(128) void k_ca(const float* __restrict__ xc,
                     const float* __restrict__ w1, const float* __restrict__ b1,
                     const float* __restrict__ w2, const float* __restrict__ b2,
                     float* __restrict__ ca){
    int b = blockIdx.x;
    int t = threadIdx.x;
    __shared__ float hid[CC/16];
    if (t < CC/16){
        float a = b1[t];
        for (int d = 0; d < CC; d++) a += w1[t*CC + d] * xc[b*CC + d];
        hid[t] = geluf(a);
    }
    __syncthreads();
    if (t < CC){
        float a = b2[t];
        #pragma unroll
        for (int i = 0; i < CC/16; i++) a += w2[t*(CC/16) + i] * hid[i];
        ca[b*CC + t] = sigmoidf(a);
    }
}

// ---------------- Kernel C: depthwise 9x9 conv, 4 px/thread sliding window (R10) -----
__global__ __launch_bounds__(256) void k_conv(const float* __restrict__ x, const float* __restrict__ w,
                       const float* __restrict__ bias, const float* __restrict__ ca,
                       float* __restrict__ x1){
    int tid4 = blockIdx.x * 256 + threadIdx.x;   // B*C*H*16 groups
    int wq4 = (tid4 & 15) * 4;                   // w0 of the 4-pixel group
    int rest = tid4 >> 4;
    int h = rest & 63;
    int bc = rest >> 6;
    int c = bc % CC; int b = bc / CC;
    const float* xp = x + (size_t)bc * LL;
    const float* wp = w + c * 81;
    float a0 = 0.f, a1 = 0.f, a2 = 0.f, a3 = 0.f;
    #pragma unroll
    for (int ky = 0; ky < 9; ky++){
        int yy = h + ky - 4;
        if (yy < 0 || yy >= HH) continue;
        const float4* row4 = (const float4*)(xp + yy*WW);
        int g = wq4 >> 2;
        float4 q0 = (wq4 >= 4)  ? row4[g-1] : make_float4(0.f,0.f,0.f,0.f);
        float4 q1 = row4[g];
        float4 q2 = (wq4 < 60)  ? row4[g+1] : make_float4(0.f,0.f,0.f,0.f);
        float v[12] = {q0.x,q0.y,q0.z,q0.w, q1.x,q1.y,q1.z,q1.w, q2.x,q2.y,q2.z,q2.w};
        const float* wr = wp + ky*9;
        #pragma unroll
        for (int kx = 0; kx < 9; kx++){
            float wk = wr[kx];
            a0 = fmaf(v[kx],   wk, a0);
            a1 = fmaf(v[kx+1], wk, a1);
            a2 = fmaf(v[kx+2], wk, a2);
            a3 = fmaf(v[kx+3], wk, a3);
        }
    }
    float sc = ca[b*CC + c];
    float bb = bias[c];
    float4 o = make_float4((a0+bb)*sc, (a1+bb)*sc, (a2+bb)*sc, (a3+bb)*sc);
    *(float4*)(x1 + (size_t)bc*LL + h*WW + wq4) = o;
}

// ---------------- Kernel E v2: LayerNorm(C)+GELU+1x1, 32-l tiles (512 blocks) --------
__global__ __launch_bounds__(256) void k_off(const float* __restrict__ x1,
                      const float* __restrict__ g, const float* __restrict__ bta,
                      const float* __restrict__ w2,
                      float* __restrict__ posy, float* __restrict__ posx, float* __restrict__ path){
    int blk = blockIdx.x;            // b*128 + tile
    int tile = blk & 127; int b = blk >> 7;
    int li = threadIdx.x & 31;
    int cg = threadIdx.x >> 5;       // 0..7
    int l = tile * 32 + li;
    const float* p = x1 + (size_t)b * CC * LL + l;
    float v[12];
    float s = 0.f, ss = 0.f;
    #pragma unroll
    for (int j = 0; j < 12; j++){
        float t = p[(size_t)(cg*12 + j) * LL];
        v[j] = t; s += t; ss += t*t;
    }
    __shared__ float ls[8][32], lss[8][32];
    ls[cg][li] = s; lss[cg][li] = ss;
    __syncthreads();
    s = 0.f; ss = 0.f;
    #pragma unroll
    for (int g2 = 0; g2 < 8; g2++){ s += ls[g2][li]; ss += lss[g2][li]; }
    float m = s * (1.0f/CC);
    float rstd = rsqrtf(ss*(1.0f/CC) - m*m + 1e-5f);
    float a0 = 0.f, a1 = 0.f, a2 = 0.f;
    #pragma unroll
    for (int j = 0; j < 12; j++){
        int c = cg*12 + j;
        float xn = (v[j]-m)*rstd*g[c] + bta[c];
        float xg = geluf(xn);
        a0 = fmaf(w2[c],      xg, a0);
        a1 = fmaf(w2[CC+c],   xg, a1);
        a2 = fmaf(w2[2*CC+c], xg, a2);
    }
    __shared__ float la[3][8][32];
    la[0][cg][li] = a0; la[1][cg][li] = a1; la[2][cg][li] = a2;
    __syncthreads();
    if (cg < 3){
        float a = 0.f;
        #pragma unroll
        for (int g2 = 0; g2 < 8; g2++) a += la[cg][g2][li];
        int h = l >> 6, ww = l & 63;
        if (cg == 0)      posy[b*LL + l] = tanhf(a)*(1.0f/63.0f) + ((2*h+1)*(1.0f/63.0f) - 1.0f);
        else if (cg == 1) posx[b*LL + l] = tanhf(a)*(1.0f/63.0f) + ((2*ww+1)*(1.0f/63.0f) - 1.0f);
        else              path[b*LL + l] = tanhf(a) + ((l + 0.5f)*(2.0f/4095.0f) - 1.0f);
    }
}

// ---------------- bilinear sample, zero padding ----------------
__device__ __forceinline__ float bilin0(const float* __restrict__ img, float gx, float gy){
    float fx = (gx + 1.f) * 31.5f;   // (W-1)/2 = 31.5
    float fy = (gy + 1.f) * 31.5f;
    float x0f = floorf(fx), y0f = floorf(fy);
    float wx = fx - x0f, wy = fy - y0f;
    int x0 = (int)x0f, y0 = (int)y0f;
    float acc = 0.f;
    bool vx0 = (x0 >= 0) & (x0 < WW), vx1 = (x0+1 >= 0) & (x0+1 < WW);
    bool vy0 = (y0 >= 0) & (y0 < HH), vy1 = (y0+1 >= 0) & (y0+1 < HH);
    if (vy0 & vx0) acc += img[y0*WW + x0]       * (1.f-wx) * (1.f-wy);
    if (vy0 & vx1) acc += img[y0*WW + x0+1]     * wx       * (1.f-wy);
    if (vy1 & vx0) acc += img[(y0+1)*WW + x0]   * (1.f-wx) * wy;
    if (vy1 & vx1) acc += img[(y0+1)*WW + x0+1] * wx       * wy;
    return acc;
}

// ---------------- Kernel F+S fused: bitonic argsort (4 blocks) || grid-sample (rest) ----
typedef unsigned long long u64s;
__device__ __forceinline__ u64s shflx64(u64s x, int m){
    int lo = __shfl_xor((int)(unsigned)x, m);
    int hi = __shfl_xor((int)(unsigned)(x >> 32), m);
    return ((u64s)(unsigned)hi << 32) | (unsigned)lo;
}
__device__ __forceinline__ void cex(u64s& a, u64s& b, bool up){
    u64s mn = a < b ? a : b;
    u64s mx = a < b ? b : a;
    a = up ? mn : mx;
    b = up ? mx : mn;
}
__global__ __launch_bounds__(1024) void k_sortsample(
        const float* __restrict__ path, int* __restrict__ idx, int* __restrict__ inv,
        const float* __restrict__ x, const float* __restrict__ rpe,
        const float* __restrict__ posy, const float* __restrict__ posx,
        float* __restrict__ xd){
    int blk = blockIdx.x;
    if (blk < BB){
        // -------- sort role: one block per batch --------
        int b = blk;
        int t = threadIdx.x;
        __shared__ u64s lds[LL];
        u64s v[4];
        #pragma unroll
        for (int r = 0; r < 4; r++){
            int e = t*4 + r;
            unsigned u = __float_as_uint(path[b*LL + e]);
            u ^= (u >> 31) ? 0xFFFFFFFFu : 0x80000000u;   // monotonic float->uint
            v[r] = ((u64s)u << 32) | (unsigned)e;
        }
        for (int kk = 2; kk <= LL; kk <<= 1){
            for (int j = kk >> 1; j > 0; j >>= 1){
                if (j >= 256){
                    __syncthreads();
                    #pragma unroll
                    for (int r = 0; r < 4; r++) lds[t*4 + r] = v[r];
                    __syncthreads();
                    #pragma unroll
                    for (int r = 0; r < 4; r++){
                        int e = t*4 + r;
                        u64s pv = lds[e ^ j];
                        bool up    = ((e & kk) == 0);
                        bool lower = ((e & j) == 0);
                        u64s mn = v[r] < pv ? v[r] : pv;
                        u64s mx = v[r] < pv ? pv : v[r];
                        v[r] = (up == lower) ? mn : mx;
                    }
                } else if (j >= 4){
                    int m = j >> 2;
                    #pragma unroll
                    for (int r = 0; r < 4; r++){
                        u64s pv = shflx64(v[r], m);
                        bool up    = (((t*4 + r) & kk) == 0);
                        bool lower = ((t & m) == 0);
                        u64s mn = v[r] < pv ? v[r] : pv;
                        u64s mx = v[r] < pv ? pv : v[r];
                        v[r] = (up == lower) ? mn : mx;
                    }
                } else if (j == 2){
                    bool up = (((t*4) & kk) == 0);
                    cex(v[0], v[2], up);
                    cex(v[1], v[3], up);
                } else { // j == 1
                    if (kk == 2){
                        cex(v[0], v[1], true);
                        cex(v[2], v[3], false);
                    } else {
                        bool up = (((t*4) & kk) == 0);
                        cex(v[0], v[1], up);
                        cex(v[2], v[3], up);
                    }
                }
            }
        }
        #pragma unroll
        for (int r = 0; r < 4; r++){
            int e = t*4 + r;
            int id = (int)(unsigned)(v[r] & 0xFFFFFFFFu);
            idx[b*LL + e] = id;
            inv[b*LL + id] = e;
        }
    } else {
        // -------- sample role: x grid-sample + rpe grid-sample -> xd --------
        int gid = (blk - BB) * 1024 + threadIdx.x; // B*C*L
        int l = gid & (LL-1); int bc = gid >> 12;
        int b = bc / CC; int c = bc % CC;
        float gy = posy[b*LL + l], gx = posx[b*LL + l];
        float v = bilin0(x + (size_t)bc * LL, gx, gy);
        int h = l >> 6, w = l & 63;
        float ky = h * (128.0f/3969.0f) - 1.0f;  // linspace(0,64,64)/63*2-1
        float kx = w * (128.0f/3969.0f) - 1.0f;
        float v2 = bilin0(rpe + (size_t)c * LL, (kx - gx) * 0.5f, (ky - gy) * 0.5f);
        xd[gid] = v + v2;
    }
}

// ---------------- Kernel G01: projection k=0 AND k=1 from ONE staged x-tile ----------
// xs[1] = xs[0] reversed, so a single 96x64 x-tile serves both scan directions (k=1
// outputs land at LL-1-l; reversed-contiguous stores, still coalesced). R13 verified
// correctness. R13 LESSON: launch position matters — this must run immediately before
// the scan so its 16 MB of dt/B/C output is still L2-warm (R13 put it first in the
// stream; the latency-bound scan then read cold inputs: 74 -> 108 us).
__global__ __launch_bounds__(192, 1) void k_proj01(const float* __restrict__ x,
    const float* __restrict__ xpw, const float* __restrict__ dtw,
    const float* __restrict__ dtb, float* __restrict__ dt,
    float* __restrict__ Bst, float* __restrict__ Cst){
    int blk = blockIdx.x;          // B*64 blocks
    int ltile = blk & 63; int b = blk >> 6;
    int lane = threadIdx.x & 63;
    int w = threadIdx.x >> 6;      // 0..2
    int l = ltile * 64 + lane;
    const float* xp = x + (size_t)b * CC * LL + l;

    __shared__ float vsh[CC*64];   // 24 KB
    #pragma unroll
    for (int j = 0; j < 32; j++){
        int d = w*32 + j;
        vsh[d*64 + lane] = xp[(size_t)d * LL];
    }
    __syncthreads();

    #pragma unroll
    for (int kk = 0; kk < 2; kk++){
        const float* __restrict__ Wk = xpw + kk*38*CC;
        int bk = b * KK + kk;
        int lk = (kk == 0) ? l : (LL-1-l);
        if (w == 0){
            float acc[RR];
            #pragma unroll
            for (int i = 0; i < RR; i++) acc[i] = 0.f;
            for (int d = 0; d < CC; d++){
                float vv = vsh[d*64 + lane];
                #pragma unroll
                for (int i = 0; i < RR; i++) acc[i] = fmaf(Wk[i*CC + d], vv, acc[i]);
            }
            const float* __restrict__ Dw = dtw + kk*CC*RR;
            const float* __restrict__ Db = dtb + kk*CC;
            float* dtp = dt + (size_t)bk * CC * LL + lk;
            #pragma unroll 8
            for (int d = 0; d < CC; d++){
                float sdt = Db[d];
                #pragma unroll
                for (int r = 0; r < RR; r++) sdt = fmaf(acc[r], Dw[d*RR + r], sdt);
                dtp[(size_t)d * LL] = softplusf(sdt);
            }
        } else if (w == 1){
            float acc[NN];
            #pragma unroll
            for (int i = 0; i < NN; i++) acc[i] = 0.f;
            for (int d = 0; d < CC; d++){
                float vv = vsh[d*64 + lane];
                #pragma unroll
                for (int i = 0; i < NN; i++) acc[i] = fmaf(Wk[(RR + i)*CC + d], vv, acc[i]);
            }
            size_t base = ((size_t)bk * LL + lk) * NN;
            #pragma unroll
            for (int q = 0; q < 4; q++){
                float4 o; o.x = acc[q*4]; o.y = acc[q*4+1]; o.z = acc[q*4+2]; o.w = acc[q*4+3];
                *(float4*)(Bst + base + q*4) = o;
            }
        } else {
            float acc[NN];
            #pragma unroll
            for (int i = 0; i < NN; i++) acc[i] = 0.f;
            for (int d = 0; d < CC; d++){
                float vv = vsh[d*64 + lane];
                #pragma unroll
                for (int i = 0; i < NN; i++) acc[i] = fmaf(Wk[(RR + NN + i)*CC + d], vv, acc[i]);
            }
            size_t base = ((size_t)bk * LL + lk) * NN;
            #pragma unroll
            for (int q = 0; q < 4; q++){
                float4 o; o.x = acc[q*4]; o.y = acc[q*4+1]; o.z = acc[q*4+2]; o.w = acc[q*4+3];
                *(float4*)(Cst + base + q*4) = o;
            }
        }
    }
}

// ---------------- Kernel G2: projection k=2 (R10 3-wave body, k hard-wired) ----------
__global__ __launch_bounds__(192, 1) void k_proj2(const float* __restrict__ xd,
    const int* __restrict__ indices, const float* __restrict__ xpw, const float* __restrict__ dtw,
    const float* __restrict__ dtb, float* __restrict__ u2, float* __restrict__ dt,
    float* __restrict__ Bst, float* __restrict__ Cst){
    int blk = blockIdx.x;          // B*64 blocks
    int ltile = blk & 63; int b = blk >> 6;
    int lane = threadIdx.x & 63;
    int w = threadIdx.x >> 6;      // 0..2
    const float* __restrict__ Wk = xpw + 2*38*CC;
    int bk = b * KK + 2;
    int l = ltile * 64 + lane;
    int srcl = indices[b*LL + l];
    const float* xp = xd + (size_t)b * CC * LL + srcl;

    __shared__ float vsh[CC*64];   // 24 KB
    #pragma unroll
    for (int j = 0; j < 32; j++){
        int d = w*32 + j;
        vsh[d*64 + lane] = xp[(size_t)d * LL];
    }
    __syncthreads();

    if (w == 0){
        float acc[RR];
        #pragma unroll
        for (int i = 0; i < RR; i++) acc[i] = 0.f;
        for (int d = 0; d < CC; d++){
            float vv = vsh[d*64 + lane];
            #pragma unroll
            for (int i = 0; i < RR; i++) acc[i] = fmaf(Wk[i*CC + d], vv, acc[i]);
        }
        const float* __restrict__ Dw = dtw + 2*CC*RR;
        const float* __restrict__ Db = dtb + 2*CC;
        float* dtp = dt + (size_t)bk * CC * LL + l;
        #pragma unroll 8
        for (int d = 0; d < CC; d++){
            float sdt = Db[d];
            #pragma unroll
            for (int r = 0; r < RR; r++) sdt = fmaf(acc[r], Dw[d*RR + r], sdt);
            dtp[(size_t)d * LL] = softplusf(sdt);
        }
    } else if (w == 1){
        float acc[NN];
        #pragma unroll
        for (int i = 0; i < NN; i++) acc[i] = 0.f;
        for (int d = 0; d < CC; d++){
            float vv = vsh[d*64 + lane];
            #pragma unroll
            for (int i = 0; i < NN; i++) acc[i] = fmaf(Wk[(RR + i)*CC + d], vv, acc[i]);
        }
        size_t base = ((size_t)bk * LL + l) * NN;
        #pragma unroll
        for (int q = 0; q < 4; q++){
            float4 o; o.x = acc[q*4]; o.y = acc[q*4+1]; o.z = acc[q*4+2]; o.w = acc[q*4+3];
            *(float4*)(Bst + base + q*4) = o;
        }
    } else {
        float acc[NN];
        #pragma unroll
        for (int i = 0; i < NN; i++) acc[i] = 0.f;
        for (int d = 0; d < CC; d++){
            float vv = vsh[d*64 + lane];
            #pragma unroll
            for (int i = 0; i < NN; i++) acc[i] = fmaf(Wk[(RR + NN + i)*CC + d], vv, acc[i]);
        }
        size_t base = ((size_t)bk * LL + l) * NN;
        #pragma unroll
        for (int q = 0; q < 4; q++){
            float4 o; o.x = acc[q*4]; o.y = acc[q*4+1]; o.z = acc[q*4+2]; o.w = acc[q*4+3];
            *(float4*)(Cst + base + q*4) = o;
        }
        float* up = u2 + (size_t)b * CC * LL + l;
        #pragma unroll 8
        for (int d = 0; d < CC; d++) up[(size_t)d * LL] = vsh[d*64 + lane];
    }
}

// ---------------- Kernel H: merged selective scan (R8-exact, measured ~72us) ---------
#define SEG 128        // segments
#define TL 32          // steps per segment
#define SROW 17        // padded row stride for sA/sB (words)
#define XROW 32        // row stride for sS/yl (words), XOR-swizzled, 16B-aligned
template<int KIND>
__device__ __forceinline__ void scan_body(int b, int d, const float* __restrict__ usrc,
    const float* __restrict__ dt, const float* __restrict__ Bst, const float* __restrict__ Cst,
    const float* __restrict__ Alog, const float* __restrict__ Ds, float* __restrict__ ys,
    float* sA, float* sB, float* sS, float* yl){
    int bk = b * KK + KIND;
    int tid = threadIdx.x;
    int ng = tid & 3;          // n = 4*ng + j
    int seg = tid >> 2;        // 0..127
    int t0 = seg * TL;
    int xsw = (seg & 7) << 2;  // XOR swizzle for sS/yl rows

    const float4 A4 = *(const float4*)(Alog + (KIND*CC + d)*NN + 4*ng);
    const float L2E = 1.4426950408889634f;
    float A2[4] = { -__expf(A4.x)*L2E, -__expf(A4.y)*L2E, -__expf(A4.z)*L2E, -__expf(A4.w)*L2E };
    float Dv = Ds[KIND*CC + d];

    const float* dtp = dt + ((size_t)bk * CC + d) * LL + t0;
    const float* ub = (KIND == 1)
        ? usrc + ((size_t)b*CC + d) * LL + (LL-4-t0)
        : usrc + ((size_t)b*CC + d) * LL + t0;
    const float* Bp = Bst + ((size_t)bk * LL + t0) * NN + 4*ng;
    const float* Cp = Cst + ((size_t)bk * LL + t0) * NN + 4*ng;
    float* yp = ys + ((size_t)bk * CC + d) * LL + t0;

    // Phase 1: local scan from h=0; emit y_loc and S (dt prefix sum) to LDS
    float h[4] = {0.f,0.f,0.f,0.f};
    float S = 0.f;
    for (int t = 0; t < TL; t += 4){
        float4 dq = *(const float4*)(dtp + t);
        float4 uq = (KIND == 1) ? *(const float4*)(ub - t) : *(const float4*)(ub + t);
        float4 Bq[4], Cq[4];
        #pragma unroll
        for (int i = 0; i < 4; i++){
            Bq[i] = *(const float4*)(Bp + (t+i)*NN);
            Cq[i] = *(const float4*)(Cp + (t+i)*NN);
        }
        float dd[4] = {dq.x, dq.y, dq.z, dq.w};
        float uu[4];
        if (KIND == 1){ uu[0]=uq.w; uu[1]=uq.z; uu[2]=uq.y; uu[3]=uq.x; }
        else          { uu[0]=uq.x; uu[1]=uq.y; uu[2]=uq.z; uu[3]=uq.w; }
        float sv[4], pv[4];
        #pragma unroll
        for (int i = 0; i < 4; i++){
            float du = dd[i] * uu[i];
            float bb[4] = {Bq[i].x, Bq[i].y, Bq[i].z, Bq[i].w};
            float cc[4] = {Cq[i].x, Cq[i].y, Cq[i].z, Cq[i].w};
            float p = 0.f;
            #pragma unroll
            for (int j = 0; j < 4; j++){
                float a = exp2f(dd[i] * A2[j]);
                h[j] = fmaf(a, h[j], du * bb[j]);
                p = fmaf(h[j], cc[j], p);
            }
            S += dd[i];
            sv[i] = S;
            p += __shfl_xor(p, 1);
            p += __shfl_xor(p, 2);
            pv[i] = fmaf(uu[i], Dv, p);
        }
        if (ng == 0){
            int xo = seg*XROW + (t ^ xsw);
            *(float4*)(sS + xo) = make_float4(sv[0], sv[1], sv[2], sv[3]);
            *(float4*)(yl + xo) = make_float4(pv[0], pv[1], pv[2], pv[3]);
        }
    }

    // Phase 2: per-wave shuffle scan over 128 segments (exclusive carries)
    #pragma unroll
    for (int j = 0; j < 4; j++){
        sA[seg*SROW + 4*ng + j] = exp2f(A2[j] * S);
        sB[seg*SROW + 4*ng + j] = h[j];
    }
    __syncthreads();
    {
        int wv = tid >> 6;         // 0..7
        int lane = tid & 63;
        #pragma unroll
        for (int nn = 0; nn < 2; nn++){
            int n = 2*wv + nn;
            float a1 = sA[(2*lane)*SROW + n],   b1 = sB[(2*lane)*SROW + n];
            float a2 = sA[(2*lane+1)*SROW + n], b2 = sB[(2*lane+1)*SROW + n];
            float ca = a1 * a2;
            float cb = fmaf(a2, b1, b2);
            #pragma unroll
            for (int off = 1; off < 64; off <<= 1){
                float ta = __shfl_up(ca, off);
                float tb = __shfl_up(cb, off);
                if (lane >= off){
                    cb = fmaf(ca, tb, cb);
                    ca *= ta;
                }
            }
            float cb_prev = __shfl_up(cb, 1);
            if (lane == 0) cb_prev = 0.f;
            sA[(2*lane)*SROW + n]   = cb_prev;
            sA[(2*lane+1)*SROW + n] = fmaf(a1, cb_prev, b1);
        }
    }
    __syncthreads();
    float hc[4];
    #pragma unroll
    for (int j = 0; j < 4; j++) hc[j] = sA[seg*SROW + 4*ng + j];

    // Phase 3: y = y_loc + C·(exp2(A2·S)∘hc) — per-step independent
    for (int t = 0; t < TL; t += 4){
        int xo = seg*XROW + (t ^ xsw);
        float4 sq = *(const float4*)(sS + xo);
        float4 Cq[4];
        #pragma unroll
        for (int i = 0; i < 4; i++) Cq[i] = *(const float4*)(Cp + (t+i)*NN);
        float sv[4] = {sq.x, sq.y, sq.z, sq.w};
        float yo[4];
        #pragma unroll
        for (int i = 0; i < 4; i++){
            float cc[4] = {Cq[i].x, Cq[i].y, Cq[i].z, Cq[i].w};
            float corr = 0.f;
            #pragma unroll
            for (int j = 0; j < 4; j++){
                float P = exp2f(sv[i] * A2[j]);
                corr = fmaf(P * hc[j], cc[j], corr);
            }
            corr += __shfl_xor(corr, 1);
            corr += __shfl_xor(corr, 2);
            yo[i] = corr;
        }
        if (ng == 0){
            float4 ylq = *(const float4*)(yl + xo);
            float4 o = make_float4(ylq.x + yo[0], ylq.y + yo[1], ylq.z + yo[2], ylq.w + yo[3]);
            *(float4*)(yp + t) = o;
        }
    }
}

__global__ __launch_bounds__(512) void k_scan_all(const float* __restrict__ x, const float* __restrict__ u2,
    const float* __restrict__ dt, const float* __restrict__ Bst, const float* __restrict__ Cst,
    const float* __restrict__ Alog, const float* __restrict__ Ds, float* __restrict__ ys){
    __shared__ float sA[SEG*SROW];
    __shared__ float sB[SEG*SROW];
    __shared__ float sS[SEG*XROW];
    __shared__ float yl[SEG*XROW];   // total LDS 50176 B
    int blk = blockIdx.x;            // KK*BB*CC
    int k = blk / (BB*CC);
    int r = blk % (BB*CC);
    int d = r % CC; int b = r / CC;
    if (k == 0)      scan_body<0>(b, d, x,  dt, Bst, Cst, Alog, Ds, ys, sA, sB, sS, yl);
    else if (k == 1) scan_body<1>(b, d, x,  dt, Bst, Cst, Alog, Ds, ys, sA, sB, sS, yl);
    else             scan_body<2>(b, d, u2, dt, Bst, Cst, Alog, Ds, ys, sA, sB, sS, yl);
}

// ---------------- Kernel I: combine 3 paths + transpose, 16-l tiles (R10) ------------
__global__ __launch_bounds__(256) void k_comb(const float* __restrict__ ys, const int* __restrict__ inv,
                                              float* __restrict__ out){
    int tile = blockIdx.x & 255; int b = blockIdx.x >> 8;
    int l0 = tile * 16;
    __shared__ float t0[CC * 17];
    __shared__ int invs[16];
    if (threadIdx.x < 16) invs[threadIdx.x] = inv[b*LL + l0 + threadIdx.x];
    __syncthreads();
    const float* y0p = ys + (size_t)(b*KK + 0) * CC * LL;
    const float* y1p = ys + (size_t)(b*KK + 1) * CC * LL;
    const float* y2p = ys + (size_t)(b*KK + 2) * CC * LL;
    #pragma unroll
    for (int it = 0; it < 6; it++){
        int e = it * 256 + threadIdx.x;    // 0..1535
        int li = e & 15; int c = e >> 4;
        int l = l0 + li;
        float v = y0p[(size_t)c*LL + l] + y1p[(size_t)c*LL + (LL-1-l)] + y2p[(size_t)c*LL + invs[li]];
        t0[c*17 + li] = v * (1.0f/3.0f);
    }
    __syncthreads();
    #pragma unroll
    for (int it = 0; it < 6; it++){
        int e = it * 256 + threadIdx.x;
        int c = e % CC; int li = e / CC;
        out[((size_t)b*LL + l0 + li) * CC + c] = t0[c*17 + li];
    }
}

extern "C" void kernel_launch(void* const* d_in, const int* in_sizes, int n_in,
                              void* d_out, int out_size, void* d_ws, size_t ws_size,
                              hipStream_t stream){
    const float* x    = (const float*)d_in[0];
    const float* xpw  = (const float*)d_in[1];
    const float* dtw  = (const float*)d_in[2];
    const float* dtb  = (const float*)d_in[3];
    const float* Alog = (const float*)d_in[4];
    const float* Ds   = (const float*)d_in[5];
    const float* c1w  = (const float*)d_in[6];
    const float* c1b  = (const float*)d_in[7];
    const float* ca1w = (const float*)d_in[8];
    const float* ca1b = (const float*)d_in[9];
    const float* ca2w = (const float*)d_in[10];
    const float* ca2b = (const float*)d_in[11];
    const float* lng  = (const float*)d_in[12];
    const float* lnb  = (const float*)d_in[13];
    const float* c2w  = (const float*)d_in[14];
    const float* rpet = (const float*)d_in[15];
    float* out = (float*)d_out;

    float* ws   = (float*)d_ws;
    float* xc   = ws;                      // 384
    float* ca   = xc + 384;                // 384
    float* x1   = ca + 384;                // B*C*L = 1572864
    float* rpe  = x1 + (size_t)BB*CC*LL;   // C*L = 393216
    float* posy = rpe + (size_t)CC*LL;     // B*L
    float* posx = posy + (size_t)BB*LL;
    float* path = posx + (size_t)BB*LL;
    float* xd   = path + (size_t)BB*LL;    // B*C*L
    int*   idx  = (int*)(xd + (size_t)BB*CC*LL);   // B*L ints
    int*   inv  = idx + (size_t)BB*LL;             // B*L ints
    float* u2   = (float*)(inv + (size_t)BB*LL);   // B*C*L
    float* dtA  = u2 + (size_t)BB*CC*LL;           // B*K*C*L = 4718592
    float* Bst  = dtA + (size_t)BB*KK*CC*LL;       // B*K*L*N = 786432
    float* Cst  = Bst + (size_t)BB*KK*LL*NN;
    float* ysA  = Cst + (size_t)BB*KK*LL*NN;       // B*K*C*L

    // Order matters (R13 lesson): proj01/proj2 run IMMEDIATELY before the scan so
    // dt/B/C stay L2-warm for the latency-bound scan.
    k_meanrpe  <<<BB*CC + (CC*LL)/256, 256, 0, stream>>>(x, xc, rpet, rpe);
    k_ca       <<<BB, 128, 0, stream>>>(xc, ca1w, ca1b, ca2w, ca2b, ca);
    k_conv     <<<(BB*CC*LL/4)/256, 256, 0, stream>>>(x, c1w, c1b, ca, x1);
    k_off      <<<BB*128, 256, 0, stream>>>(x1, lng, lnb, c2w, posy, posx, path);
    k_sortsample<<<BB + (BB*CC*LL)/1024, 1024, 0, stream>>>(path, idx, inv, x, rpe, posy, posx, xd);
    k_proj01   <<<BB*64, 192, 0, stream>>>(x, xpw, dtw, dtb, dtA, Bst, Cst);
    k_proj2    <<<BB*64, 192, 0, stream>>>(xd, idx, xpw, dtw, dtb, u2, dtA, Bst, Cst);
    k_scan_all <<<KK*BB*CC, 512, 0, stream>>>(x, u2, dtA, Bst, Cst, Alog, Ds, ysA);
    k_comb     <<<BB*256, 256, 0, stream>>>(ysA, inv, out);
}

// Round 15
// 287.789 us; speedup vs baseline: 1.3887x; 1.1494x over previous
//
#include <hip/hip_runtime.h>

#define BB 4
#define CC 96
#define HH 64
#define WW 64
#define LL 4096
#define KK 3
#define RR 6
#define NN 16

__device__ __forceinline__ float geluf(float x){
    return 0.5f * x * (1.0f + erff(x * 0.70710678118654752f));
}
__device__ __forceinline__ float softplusf(float x){
    return fmaxf(x, 0.0f) + log1pf(expf(-fabsf(x)));
}
__device__ __forceinline__ float sigmoidf(float x){
    return 1.0f / (1.0f + expf(-x));
}

// ---------------- Kernel A+D fused: spatial mean (384 blocks) || rpe resize (1536) ----
__global__ __launch_bounds__(256) void k_meanrpe(const float* __restrict__ x, float* __restrict__ xc,
                                                 const float* __restrict__ rpet, float* __restrict__ rpe){
    int blk = blockIdx.x;
    if (blk < BB*CC){
        const float* p = x + (size_t)blk * LL;
        float s = 0.f;
        for (int i = threadIdx.x; i < LL; i += 256) s += p[i];
        __shared__ float red[256];
        red[threadIdx.x] = s; __syncthreads();
        for (int st = 128; st > 0; st >>= 1){
            if (threadIdx.x < st) red[threadIdx.x] += red[threadIdx.x + st];
            __syncthreads();
        }
        if (threadIdx.x == 0) xc[blk] = red[0] * (1.0f / LL);
    } else {
        int gid = (blk - BB*CC) * 256 + threadIdx.x; // C*L
        int l = gid & (LL-1); int c = gid >> 12;
        int h = l >> 6, w = l & 63;
        float sy = fmaxf((h + 0.5f) * (7.0f/64.0f) - 0.5f, 0.f);
        float sx = fmaxf((w + 0.5f) * (7.0f/64.0f) - 0.5f, 0.f);
        int y0 = (int)floorf(sy); int x0 = (int)floorf(sx);
        float wy = sy - (float)y0, wx = sx - (float)x0;
        int y1 = min(y0 + 1, 6), x1i = min(x0 + 1, 6);
        const float* tp = rpet + c * 49;
        float r0 = tp[y0*7 + x0] * (1.f - wy) + tp[y1*7 + x0] * wy;
        float r1 = tp[y0*7 + x1i] * (1.f - wy) + tp[y1*7 + x1i] * wy;
        rpe[gid] = r0 * (1.f - wx) + r1 * wx;
    }
}

// ---------------- Kernel B: channel-attention MLP ----------------
__global__ __launch_bounds__(128) void k_ca(const float* __restrict__ xc,
                     const float* __restrict__ w1, const float* __restrict__ b1,
                     const float* __restrict__ w2, const float* __restrict__ b2,
                     float* __restrict__ ca){
    int b = blockIdx.x;
    int t = threadIdx.x;
    __shared__ float hid[CC/16];
    if (t < CC/16){
        float a = b1[t];
        for (int d = 0; d < CC; d++) a += w1[t*CC + d] * xc[b*CC + d];
        hid[t] = geluf(a);
    }
    __syncthreads();
    if (t < CC){
        float a = b2[t];
        #pragma unroll
        for (int i = 0; i < CC/16; i++) a += w2[t*(CC/16) + i] * hid[i];
        ca[b*CC + t] = sigmoidf(a);
    }
}

// ---------------- Kernel C: depthwise 9x9 conv, 4 px/thread sliding window (R10) -----
__global__ __launch_bounds__(256) void k_conv(const float* __restrict__ x, const float* __restrict__ w,
                       const float* __restrict__ bias, const float* __restrict__ ca,
                       float* __restrict__ x1){
    int tid4 = blockIdx.x * 256 + threadIdx.x;   // B*C*H*16 groups
    int wq4 = (tid4 & 15) * 4;                   // w0 of the 4-pixel group
    int rest = tid4 >> 4;
    int h = rest & 63;
    int bc = rest >> 6;
    int c = bc % CC; int b = bc / CC;
    const float* xp = x + (size_t)bc * LL;
    const float* wp = w + c * 81;
    float a0 = 0.f, a1 = 0.f, a2 = 0.f, a3 = 0.f;
    #pragma unroll
    for (int ky = 0; ky < 9; ky++){
        int yy = h + ky - 4;
        if (yy < 0 || yy >= HH) continue;
        const float4* row4 = (const float4*)(xp + yy*WW);
        int g = wq4 >> 2;
        float4 q0 = (wq4 >= 4)  ? row4[g-1] : make_float4(0.f,0.f,0.f,0.f);
        float4 q1 = row4[g];
        float4 q2 = (wq4 < 60)  ? row4[g+1] : make_float4(0.f,0.f,0.f,0.f);
        float v[12] = {q0.x,q0.y,q0.z,q0.w, q1.x,q1.y,q1.z,q1.w, q2.x,q2.y,q2.z,q2.w};
        const float* wr = wp + ky*9;
        #pragma unroll
        for (int kx = 0; kx < 9; kx++){
            float wk = wr[kx];
            a0 = fmaf(v[kx],   wk, a0);
            a1 = fmaf(v[kx+1], wk, a1);
            a2 = fmaf(v[kx+2], wk, a2);
            a3 = fmaf(v[kx+3], wk, a3);
        }
    }
    float sc = ca[b*CC + c];
    float bb = bias[c];
    float4 o = make_float4((a0+bb)*sc, (a1+bb)*sc, (a2+bb)*sc, (a3+bb)*sc);
    *(float4*)(x1 + (size_t)bc*LL + h*WW + wq4) = o;
}

// ---------------- Kernel E v2: LayerNorm(C)+GELU+1x1, 32-l tiles (512 blocks) --------
__global__ __launch_bounds__(256) void k_off(const float* __restrict__ x1,
                      const float* __restrict__ g, const float* __restrict__ bta,
                      const float* __restrict__ w2,
                      float* __restrict__ posy, float* __restrict__ posx, float* __restrict__ path){
    int blk = blockIdx.x;            // b*128 + tile
    int tile = blk & 127; int b = blk >> 7;
    int li = threadIdx.x & 31;
    int cg = threadIdx.x >> 5;       // 0..7
    int l = tile * 32 + li;
    const float* p = x1 + (size_t)b * CC * LL + l;
    float v[12];
    float s = 0.f, ss = 0.f;
    #pragma unroll
    for (int j = 0; j < 12; j++){
        float t = p[(size_t)(cg*12 + j) * LL];
        v[j] = t; s += t; ss += t*t;
    }
    __shared__ float ls[8][32], lss[8][32];
    ls[cg][li] = s; lss[cg][li] = ss;
    __syncthreads();
    s = 0.f; ss = 0.f;
    #pragma unroll
    for (int g2 = 0; g2 < 8; g2++){ s += ls[g2][li]; ss += lss[g2][li]; }
    float m = s * (1.0f/CC);
    float rstd = rsqrtf(ss*(1.0f/CC) - m*m + 1e-5f);
    float a0 = 0.f, a1 = 0.f, a2 = 0.f;
    #pragma unroll
    for (int j = 0; j < 12; j++){
        int c = cg*12 + j;
        float xn = (v[j]-m)*rstd*g[c] + bta[c];
        float xg = geluf(xn);
        a0 = fmaf(w2[c],      xg, a0);
        a1 = fmaf(w2[CC+c],   xg, a1);
        a2 = fmaf(w2[2*CC+c], xg, a2);
    }
    __shared__ float la[3][8][32];
    la[0][cg][li] = a0; la[1][cg][li] = a1; la[2][cg][li] = a2;
    __syncthreads();
    if (cg < 3){
        float a = 0.f;
        #pragma unroll
        for (int g2 = 0; g2 < 8; g2++) a += la[cg][g2][li];
        int h = l >> 6, ww = l & 63;
        if (cg == 0)      posy[b*LL + l] = tanhf(a)*(1.0f/63.0f) + ((2*h+1)*(1.0f/63.0f) - 1.0f);
        else if (cg == 1) posx[b*LL + l] = tanhf(a)*(1.0f/63.0f) + ((2*ww+1)*(1.0f/63.0f) - 1.0f);
        else              path[b*LL + l] = tanhf(a) + ((l + 0.5f)*(2.0f/4095.0f) - 1.0f);
    }
}

// ---------------- bilinear sample, zero padding ----------------
__device__ __forceinline__ float bilin0(const float* __restrict__ img, float gx, float gy){
    float fx = (gx + 1.f) * 31.5f;   // (W-1)/2 = 31.5
    float fy = (gy + 1.f) * 31.5f;
    float x0f = floorf(fx), y0f = floorf(fy);
    float wx = fx - x0f, wy = fy - y0f;
    int x0 = (int)x0f, y0 = (int)y0f;
    float acc = 0.f;
    bool vx0 = (x0 >= 0) & (x0 < WW), vx1 = (x0+1 >= 0) & (x0+1 < WW);
    bool vy0 = (y0 >= 0) & (y0 < HH), vy1 = (y0+1 >= 0) & (y0+1 < HH);
    if (vy0 & vx0) acc += img[y0*WW + x0]       * (1.f-wx) * (1.f-wy);
    if (vy0 & vx1) acc += img[y0*WW + x0+1]     * wx       * (1.f-wy);
    if (vy1 & vx0) acc += img[(y0+1)*WW + x0]   * (1.f-wx) * wy;
    if (vy1 & vx1) acc += img[(y0+1)*WW + x0+1] * wx       * wy;
    return acc;
}

// ---------------- Kernel F+S fused: bitonic argsort (4 blocks) || grid-sample (rest) ----
typedef unsigned long long u64s;
__device__ __forceinline__ u64s shflx64(u64s x, int m){
    int lo = __shfl_xor((int)(unsigned)x, m);
    int hi = __shfl_xor((int)(unsigned)(x >> 32), m);
    return ((u64s)(unsigned)hi << 32) | (unsigned)lo;
}
__device__ __forceinline__ void cex(u64s& a, u64s& b, bool up){
    u64s mn = a < b ? a : b;
    u64s mx = a < b ? b : a;
    a = up ? mn : mx;
    b = up ? mx : mn;
}
__global__ __launch_bounds__(1024) void k_sortsample(
        const float* __restrict__ path, int* __restrict__ idx, int* __restrict__ inv,
        const float* __restrict__ x, const float* __restrict__ rpe,
        const float* __restrict__ posy, const float* __restrict__ posx,
        float* __restrict__ xd){
    int blk = blockIdx.x;
    if (blk < BB){
        // -------- sort role: one block per batch --------
        int b = blk;
        int t = threadIdx.x;
        __shared__ u64s lds[LL];
        u64s v[4];
        #pragma unroll
        for (int r = 0; r < 4; r++){
            int e = t*4 + r;
            unsigned u = __float_as_uint(path[b*LL + e]);
            u ^= (u >> 31) ? 0xFFFFFFFFu : 0x80000000u;   // monotonic float->uint
            v[r] = ((u64s)u << 32) | (unsigned)e;
        }
        for (int kk = 2; kk <= LL; kk <<= 1){
            for (int j = kk >> 1; j > 0; j >>= 1){
                if (j >= 256){
                    __syncthreads();
                    #pragma unroll
                    for (int r = 0; r < 4; r++) lds[t*4 + r] = v[r];
                    __syncthreads();
                    #pragma unroll
                    for (int r = 0; r < 4; r++){
                        int e = t*4 + r;
                        u64s pv = lds[e ^ j];
                        bool up    = ((e & kk) == 0);
                        bool lower = ((e & j) == 0);
                        u64s mn = v[r] < pv ? v[r] : pv;
                        u64s mx = v[r] < pv ? pv : v[r];
                        v[r] = (up == lower) ? mn : mx;
                    }
                } else if (j >= 4){
                    int m = j >> 2;
                    #pragma unroll
                    for (int r = 0; r < 4; r++){
                        u64s pv = shflx64(v[r], m);
                        bool up    = (((t*4 + r) & kk) == 0);
                        bool lower = ((t & m) == 0);
                        u64s mn = v[r] < pv ? v[r] : pv;
                        u64s mx = v[r] < pv ? pv : v[r];
                        v[r] = (up == lower) ? mn : mx;
                    }
                } else if (j == 2){
                    bool up = (((t*4) & kk) == 0);
                    cex(v[0], v[2], up);
                    cex(v[1], v[3], up);
                } else { // j == 1
                    if (kk == 2){
                        cex(v[0], v[1], true);
                        cex(v[2], v[3], false);
                    } else {
                        bool up = (((t*4) & kk) == 0);
                        cex(v[0], v[1], up);
                        cex(v[2], v[3], up);
                    }
                }
            }
        }
        #pragma unroll
        for (int r = 0; r < 4; r++){
            int e = t*4 + r;
            int id = (int)(unsigned)(v[r] & 0xFFFFFFFFu);
            idx[b*LL + e] = id;
            inv[b*LL + id] = e;
        }
    } else {
        // -------- sample role: x grid-sample + rpe grid-sample -> xd --------
        int gid = (blk - BB) * 1024 + threadIdx.x; // B*C*L
        int l = gid & (LL-1); int bc = gid >> 12;
        int b = bc / CC; int c = bc % CC;
        float gy = posy[b*LL + l], gx = posx[b*LL + l];
        float v = bilin0(x + (size_t)bc * LL, gx, gy);
        int h = l >> 6, w = l & 63;
        float ky = h * (128.0f/3969.0f) - 1.0f;  // linspace(0,64,64)/63*2-1
        float kx = w * (128.0f/3969.0f) - 1.0f;
        float v2 = bilin0(rpe + (size_t)c * LL, (kx - gx) * 0.5f, (ky - gy) * 0.5f);
        xd[gid] = v + v2;
    }
}

// ---------------- Kernel G: projection, 3-wave output split + shared v in LDS --------
// R10-exact (295.8us run). R13/R14 LESSON: the proj01 "stage once, compute 2 k's"
// variant cut blocks 768->256 and doubled serial work -> 1 block/CU latency-exposed
// kernel at 74us. For latency-bound kernels, never trade block parallelism for
// arithmetic reuse. This unified form does all 3 k's in <40us via 768 blocks.
__global__ __launch_bounds__(192, 1) void k_proj(const float* __restrict__ x, const float* __restrict__ xd,
    const int* __restrict__ indices, const float* __restrict__ xpw, const float* __restrict__ dtw,
    const float* __restrict__ dtb, float* __restrict__ u2, float* __restrict__ dt,
    float* __restrict__ Bst, float* __restrict__ Cst){
    int blk = blockIdx.x;          // B*K*64 blocks
    int ltile = blk & 63; int bk = blk >> 6;
    int k = bk % KK; int b = bk / KK;
    int lane = threadIdx.x & 63;
    int w = threadIdx.x >> 6;      // 0..2
    const float* __restrict__ Wk = xpw + k*38*CC;
    int l = ltile * 64 + lane;
    int srcl = (k == 0) ? l : (k == 1 ? (LL-1-l) : indices[b*LL + l]);
    const float* xp = (k == 2 ? xd : x) + (size_t)b * CC * LL + srcl;

    __shared__ float vsh[CC*64];   // 24 KB
    #pragma unroll
    for (int j = 0; j < 32; j++){
        int d = w*32 + j;
        vsh[d*64 + lane] = xp[(size_t)d * LL];
    }
    __syncthreads();

    if (w == 0){
        float acc[RR];
        #pragma unroll
        for (int i = 0; i < RR; i++) acc[i] = 0.f;
        for (int d = 0; d < CC; d++){
            float vv = vsh[d*64 + lane];
            #pragma unroll
            for (int i = 0; i < RR; i++) acc[i] = fmaf(Wk[i*CC + d], vv, acc[i]);
        }
        const float* __restrict__ Dw = dtw + k*CC*RR;
        const float* __restrict__ Db = dtb + k*CC;
        float* dtp = dt + (size_t)bk * CC * LL + l;
        #pragma unroll 8
        for (int d = 0; d < CC; d++){
            float sdt = Db[d];
            #pragma unroll
            for (int r = 0; r < RR; r++) sdt = fmaf(acc[r], Dw[d*RR + r], sdt);
            dtp[(size_t)d * LL] = softplusf(sdt);
        }
    } else if (w == 1){
        float acc[NN];
        #pragma unroll
        for (int i = 0; i < NN; i++) acc[i] = 0.f;
        for (int d = 0; d < CC; d++){
            float vv = vsh[d*64 + lane];
            #pragma unroll
            for (int i = 0; i < NN; i++) acc[i] = fmaf(Wk[(RR + i)*CC + d], vv, acc[i]);
        }
        size_t base = ((size_t)bk * LL + l) * NN;
        #pragma unroll
        for (int q = 0; q < 4; q++){
            float4 o; o.x = acc[q*4]; o.y = acc[q*4+1]; o.z = acc[q*4+2]; o.w = acc[q*4+3];
            *(float4*)(Bst + base + q*4) = o;
        }
    } else {
        float acc[NN];
        #pragma unroll
        for (int i = 0; i < NN; i++) acc[i] = 0.f;
        for (int d = 0; d < CC; d++){
            float vv = vsh[d*64 + lane];
            #pragma unroll
            for (int i = 0; i < NN; i++) acc[i] = fmaf(Wk[(RR + NN + i)*CC + d], vv, acc[i]);
        }
        size_t base = ((size_t)bk * LL + l) * NN;
        #pragma unroll
        for (int q = 0; q < 4; q++){
            float4 o; o.x = acc[q*4]; o.y = acc[q*4+1]; o.z = acc[q*4+2]; o.w = acc[q*4+3];
            *(float4*)(Cst + base + q*4) = o;
        }
        if (k == 2){
            float* up = u2 + (size_t)b * CC * LL + l;
            #pragma unroll 8
            for (int d = 0; d < CC; d++) up[(size_t)d * LL] = vsh[d*64 + lane];
        }
    }
}

// ---------------- Kernel H: merged selective scan (R8-exact, measured ~72us) ---------
#define SEG 128        // segments
#define TL 32          // steps per segment
#define SROW 17        // padded row stride for sA/sB (words)
#define XROW 32        // row stride for sS/yl (words), XOR-swizzled, 16B-aligned
template<int KIND>
__device__ __forceinline__ void scan_body(int b, int d, const float* __restrict__ usrc,
    const float* __restrict__ dt, const float* __restrict__ Bst, const float* __restrict__ Cst,
    const float* __restrict__ Alog, const float* __restrict__ Ds, float* __restrict__ ys,
    float* sA, float* sB, float* sS, float* yl){
    int bk = b * KK + KIND;
    int tid = threadIdx.x;
    int ng = tid & 3;          // n = 4*ng + j
    int seg = tid >> 2;        // 0..127
    int t0 = seg * TL;
    int xsw = (seg & 7) << 2;  // XOR swizzle for sS/yl rows

    const float4 A4 = *(const float4*)(Alog + (KIND*CC + d)*NN + 4*ng);
    const float L2E = 1.4426950408889634f;
    float A2[4] = { -__expf(A4.x)*L2E, -__expf(A4.y)*L2E, -__expf(A4.z)*L2E, -__expf(A4.w)*L2E };
    float Dv = Ds[KIND*CC + d];

    const float* dtp = dt + ((size_t)bk * CC + d) * LL + t0;
    const float* ub = (KIND == 1)
        ? usrc + ((size_t)b*CC + d) * LL + (LL-4-t0)
        : usrc + ((size_t)b*CC + d) * LL + t0;
    const float* Bp = Bst + ((size_t)bk * LL + t0) * NN + 4*ng;
    const float* Cp = Cst + ((size_t)bk * LL + t0) * NN + 4*ng;
    float* yp = ys + ((size_t)bk * CC + d) * LL + t0;

    // Phase 1: local scan from h=0; emit y_loc and S (dt prefix sum) to LDS
    float h[4] = {0.f,0.f,0.f,0.f};
    float S = 0.f;
    for (int t = 0; t < TL; t += 4){
        float4 dq = *(const float4*)(dtp + t);
        float4 uq = (KIND == 1) ? *(const float4*)(ub - t) : *(const float4*)(ub + t);
        float4 Bq[4], Cq[4];
        #pragma unroll
        for (int i = 0; i < 4; i++){
            Bq[i] = *(const float4*)(Bp + (t+i)*NN);
            Cq[i] = *(const float4*)(Cp + (t+i)*NN);
        }
        float dd[4] = {dq.x, dq.y, dq.z, dq.w};
        float uu[4];
        if (KIND == 1){ uu[0]=uq.w; uu[1]=uq.z; uu[2]=uq.y; uu[3]=uq.x; }
        else          { uu[0]=uq.x; uu[1]=uq.y; uu[2]=uq.z; uu[3]=uq.w; }
        float sv[4], pv[4];
        #pragma unroll
        for (int i = 0; i < 4; i++){
            float du = dd[i] * uu[i];
            float bb[4] = {Bq[i].x, Bq[i].y, Bq[i].z, Bq[i].w};
            float cc[4] = {Cq[i].x, Cq[i].y, Cq[i].z, Cq[i].w};
            float p = 0.f;
            #pragma unroll
            for (int j = 0; j < 4; j++){
                float a = exp2f(dd[i] * A2[j]);
                h[j] = fmaf(a, h[j], du * bb[j]);
                p = fmaf(h[j], cc[j], p);
            }
            S += dd[i];
            sv[i] = S;
            p += __shfl_xor(p, 1);
            p += __shfl_xor(p, 2);
            pv[i] = fmaf(uu[i], Dv, p);
        }
        if (ng == 0){
            int xo = seg*XROW + (t ^ xsw);
            *(float4*)(sS + xo) = make_float4(sv[0], sv[1], sv[2], sv[3]);
            *(float4*)(yl + xo) = make_float4(pv[0], pv[1], pv[2], pv[3]);
        }
    }

    // Phase 2: per-wave shuffle scan over 128 segments (exclusive carries)
    #pragma unroll
    for (int j = 0; j < 4; j++){
        sA[seg*SROW + 4*ng + j] = exp2f(A2[j] * S);
        sB[seg*SROW + 4*ng + j] = h[j];
    }
    __syncthreads();
    {
        int wv = tid >> 6;         // 0..7
        int lane = tid & 63;
        #pragma unroll
        for (int nn = 0; nn < 2; nn++){
            int n = 2*wv + nn;
            float a1 = sA[(2*lane)*SROW + n],   b1 = sB[(2*lane)*SROW + n];
            float a2 = sA[(2*lane+1)*SROW + n], b2 = sB[(2*lane+1)*SROW + n];
            float ca = a1 * a2;
            float cb = fmaf(a2, b1, b2);
            #pragma unroll
            for (int off = 1; off < 64; off <<= 1){
                float ta = __shfl_up(ca, off);
                float tb = __shfl_up(cb, off);
                if (lane >= off){
                    cb = fmaf(ca, tb, cb);
                    ca *= ta;
                }
            }
            float cb_prev = __shfl_up(cb, 1);
            if (lane == 0) cb_prev = 0.f;
            sA[(2*lane)*SROW + n]   = cb_prev;
            sA[(2*lane+1)*SROW + n] = fmaf(a1, cb_prev, b1);
        }
    }
    __syncthreads();
    float hc[4];
    #pragma unroll
    for (int j = 0; j < 4; j++) hc[j] = sA[seg*SROW + 4*ng + j];

    // Phase 3: y = y_loc + C·(exp2(A2·S)∘hc) — per-step independent
    for (int t = 0; t < TL; t += 4){
        int xo = seg*XROW + (t ^ xsw);
        float4 sq = *(const float4*)(sS + xo);
        float4 Cq[4];
        #pragma unroll
        for (int i = 0; i < 4; i++) Cq[i] = *(const float4*)(Cp + (t+i)*NN);
        float sv[4] = {sq.x, sq.y, sq.z, sq.w};
        float yo[4];
        #pragma unroll
        for (int i = 0; i < 4; i++){
            float cc[4] = {Cq[i].x, Cq[i].y, Cq[i].z, Cq[i].w};
            float corr = 0.f;
            #pragma unroll
            for (int j = 0; j < 4; j++){
                float P = exp2f(sv[i] * A2[j]);
                corr = fmaf(P * hc[j], cc[j], corr);
            }
            corr += __shfl_xor(corr, 1);
            corr += __shfl_xor(corr, 2);
            yo[i] = corr;
        }
        if (ng == 0){
            float4 ylq = *(const float4*)(yl + xo);
            float4 o = make_float4(ylq.x + yo[0], ylq.y + yo[1], ylq.z + yo[2], ylq.w + yo[3]);
            *(float4*)(yp + t) = o;
        }
    }
}

__global__ __launch_bounds__(512) void k_scan_all(const float* __restrict__ x, const float* __restrict__ u2,
    const float* __restrict__ dt, const float* __restrict__ Bst, const float* __restrict__ Cst,
    const float* __restrict__ Alog, const float* __restrict__ Ds, float* __restrict__ ys){
    __shared__ float sA[SEG*SROW];
    __shared__ float sB[SEG*SROW];
    __shared__ float sS[SEG*XROW];
    __shared__ float yl[SEG*XROW];   // total LDS 50176 B
    int blk = blockIdx.x;            // KK*BB*CC
    int k = blk / (BB*CC);
    int r = blk % (BB*CC);
    int d = r % CC; int b = r / CC;
    if (k == 0)      scan_body<0>(b, d, x,  dt, Bst, Cst, Alog, Ds, ys, sA, sB, sS, yl);
    else if (k == 1) scan_body<1>(b, d, x,  dt, Bst, Cst, Alog, Ds, ys, sA, sB, sS, yl);
    else             scan_body<2>(b, d, u2, dt, Bst, Cst, Alog, Ds, ys, sA, sB, sS, yl);
}

// ---------------- Kernel I: combine 3 paths + transpose, 16-l tiles (R10) ------------
__global__ __launch_bounds__(256) void k_comb(const float* __restrict__ ys, const int* __restrict__ inv,
                                              float* __restrict__ out){
    int tile = blockIdx.x & 255; int b = blockIdx.x >> 8;
    int l0 = tile * 16;
    __shared__ float t0[CC * 17];
    __shared__ int invs[16];
    if (threadIdx.x < 16) invs[threadIdx.x] = inv[b*LL + l0 + threadIdx.x];
    __syncthreads();
    const float* y0p = ys + (size_t)(b*KK + 0) * CC * LL;
    const float* y1p = ys + (size_t)(b*KK + 1) * CC * LL;
    const float* y2p = ys + (size_t)(b*KK + 2) * CC * LL;
    #pragma unroll
    for (int it = 0; it < 6; it++){
        int e = it * 256 + threadIdx.x;    // 0..1535
        int li = e & 15; int c = e >> 4;
        int l = l0 + li;
        float v = y0p[(size_t)c*LL + l] + y1p[(size_t)c*LL + (LL-1-l)] + y2p[(size_t)c*LL + invs[li]];
        t0[c*17 + li] = v * (1.0f/3.0f);
    }
    __syncthreads();
    #pragma unroll
    for (int it = 0; it < 6; it++){
        int e = it * 256 + threadIdx.x;
        int c = e % CC; int li = e / CC;
        out[((size_t)b*LL + l0 + li) * CC + c] = t0[c*17 + li];
    }
}

extern "C" void kernel_launch(void* const* d_in, const int* in_sizes, int n_in,
                              void* d_out, int out_size, void* d_ws, size_t ws_size,
                              hipStream_t stream){
    const float* x    = (const float*)d_in[0];
    const float* xpw  = (const float*)d_in[1];
    const float* dtw  = (const float*)d_in[2];
    const float* dtb  = (const float*)d_in[3];
    const float* Alog = (const float*)d_in[4];
    const float* Ds   = (const float*)d_in[5];
    const float* c1w  = (const float*)d_in[6];
    const float* c1b  = (const float*)d_in[7];
    const float* ca1w = (const float*)d_in[8];
    const float* ca1b = (const float*)d_in[9];
    const float* ca2w = (const float*)d_in[10];
    const float* ca2b = (const float*)d_in[11];
    const float* lng  = (const float*)d_in[12];
    const float* lnb  = (const float*)d_in[13];
    const float* c2w  = (const float*)d_in[14];
    const float* rpet = (const float*)d_in[15];
    float* out = (float*)d_out;

    float* ws   = (float*)d_ws;
    float* xc   = ws;                      // 384
    float* ca   = xc + 384;                // 384
    float* x1   = ca + 384;                // B*C*L = 1572864
    float* rpe  = x1 + (size_t)BB*CC*LL;   // C*L = 393216
    float* posy = rpe + (size_t)CC*LL;     // B*L
    float* posx = posy + (size_t)BB*LL;
    float* path = posx + (size_t)BB*LL;
    float* xd   = path + (size_t)BB*LL;    // B*C*L
    int*   idx  = (int*)(xd + (size_t)BB*CC*LL);   // B*L ints
    int*   inv  = idx + (size_t)BB*LL;             // B*L ints
    float* u2   = (float*)(inv + (size_t)BB*LL);   // B*C*L
    float* dtA  = u2 + (size_t)BB*CC*LL;           // B*K*C*L = 4718592
    float* Bst  = dtA + (size_t)BB*KK*CC*LL;       // B*K*L*N = 786432
    float* Cst  = Bst + (size_t)BB*KK*LL*NN;
    float* ysA  = Cst + (size_t)BB*KK*LL*NN;       // B*K*C*L

    k_meanrpe  <<<BB*CC + (CC*LL)/256, 256, 0, stream>>>(x, xc, rpet, rpe);
    k_ca       <<<BB, 128, 0, stream>>>(xc, ca1w, ca1b, ca2w, ca2b, ca);
    k_conv     <<<(BB*CC*LL/4)/256, 256, 0, stream>>>(x, c1w, c1b, ca, x1);
    k_off      <<<BB*128, 256, 0, stream>>>(x1, lng, lnb, c2w, posy, posx, path);
    k_sortsample<<<BB + (BB*CC*LL)/1024, 1024, 0, stream>>>(path, idx, inv, x, rpe, posy, posx, xd);
    k_proj     <<<BB*KK*64, 192, 0, stream>>>(x, xd, idx, xpw, dtw, dtb, u2, dtA, Bst, Cst);
    k_scan_all <<<KK*BB*CC, 512, 0, stream>>>(x, u2, dtA, Bst, Cst, Alog, Ds, ysA);
    k_comb     <<<BB*256, 256, 0, stream>>>(ysA, inv, out);
}